// Round 4
// baseline (495.577 us; speedup 1.0000x reference)
//
#include <hip/hip_runtime.h>

#define N_CLASSES 128

// Native clang vector type -- __builtin_nontemporal_load rejects HIP's
// float4 class wrapper but accepts ext_vector_type.
typedef float f4 __attribute__((ext_vector_type(4)));

// 4 lanes per row. Lane l (l=0..3) holds float4s {l, l+4, ..., l+28} of the
// 32-float4 row. All 16 loads issue as NON-TEMPORAL (nt: no-allocate,
// streaming) -- testing whether the ~3.3 TB/s read plateau is the L3
// hit/allocate path pacing read returns; HBM write-side proves 6.6 TB/s.
// Shuffle reduces are 2 steps (xor 1,2 within a quad -> DPP). Single pass:
//   loss = (m + log(sum exp(yh - m))) * sum(y) - sum(y * yh)
// argmax(y): joint max-value reduce, then first-occurrence index by equality
// match (descending overwrite) + min-index reduce.
__global__ __launch_bounds__(256, 4) void class_loss_kernel(
    const float* __restrict__ y_hat,
    const float* __restrict__ y,
    float* __restrict__ ws,   // [0..127] class sums, [128..255] class counts
    int B)
{
    __shared__ float s_sum[N_CLASSES];
    __shared__ float s_cnt[N_CLASSES];
    const int tid = threadIdx.x;
    for (int i = tid; i < N_CLASSES; i += blockDim.x) { s_sum[i] = 0.f; s_cnt[i] = 0.f; }
    __syncthreads();

    const int lane    = tid & 3;                                   // lane within quad
    const int group   = (blockIdx.x * blockDim.x + tid) >> 2;      // global row id base
    const int ngroups = (gridDim.x * blockDim.x) >> 2;

    const f4* __restrict__ ph = (const f4*)y_hat;
    const f4* __restrict__ pt = (const f4*)y;

    for (int row = group; row < B; row += ngroups) {
        const size_t base = (size_t)row * (N_CLASSES / 4) + lane;

        f4 h[8], t[8];
        #pragma unroll
        for (int k = 0; k < 8; ++k) h[k] = __builtin_nontemporal_load(ph + base + 4 * k);
        #pragma unroll
        for (int k = 0; k < 8; ++k) t[k] = __builtin_nontemporal_load(pt + base + 4 * k);

        // local maxes: m over y_hat (softmax), bv over y (argmax value)
        float m = -INFINITY, bv = -INFINITY;
        #pragma unroll
        for (int k = 0; k < 8; ++k) {
            m  = fmaxf(m,  fmaxf(fmaxf(h[k].x, h[k].y), fmaxf(h[k].z, h[k].w)));
            bv = fmaxf(bv, fmaxf(fmaxf(t[k].x, t[k].y), fmaxf(t[k].z, t[k].w)));
        }
        m  = fmaxf(m,  __shfl_xor(m,  1));
        m  = fmaxf(m,  __shfl_xor(m,  2));
        bv = fmaxf(bv, __shfl_xor(bv, 1));
        bv = fmaxf(bv, __shfl_xor(bv, 2));

        // partials: sum exp, dot(y, y_hat), sum y
        float s = 0.f, dot = 0.f, sy = 0.f;
        #pragma unroll
        for (int k = 0; k < 8; ++k) {
            s   += __expf(h[k].x - m) + __expf(h[k].y - m)
                 + __expf(h[k].z - m) + __expf(h[k].w - m);
            dot += t[k].x * h[k].x + t[k].y * h[k].y
                 + t[k].z * h[k].z + t[k].w * h[k].w;
            sy  += (t[k].x + t[k].y) + (t[k].z + t[k].w);
        }

        // first index where y == bv: descending overwrite -> smallest match.
        // class index of component c of float4 k in lane l: (l + 4k)*4 + c
        int bi = N_CLASSES;
        #pragma unroll
        for (int k = 7; k >= 0; --k) {
            const int e = (lane + 4 * k) * 4;
            if (t[k].w == bv) bi = e + 3;
            if (t[k].z == bv) bi = e + 2;
            if (t[k].y == bv) bi = e + 1;
            if (t[k].x == bv) bi = e;
        }

        #pragma unroll
        for (int o = 2; o >= 1; o >>= 1) {
            s   += __shfl_xor(s,   o);
            dot += __shfl_xor(dot, o);
            sy  += __shfl_xor(sy,  o);
            bi   = min(bi, __shfl_xor(bi, o));
        }

        if (lane == 0) {
            float loss = (m + __logf(s)) * sy - dot;
            atomicAdd(&s_sum[bi], loss);
            atomicAdd(&s_cnt[bi], 1.0f);
        }
    }

    __syncthreads();
    for (int i = tid; i < N_CLASSES; i += blockDim.x) {
        if (s_cnt[i] > 0.f) {
            atomicAdd(&ws[i], s_sum[i]);
            atomicAdd(&ws[N_CLASSES + i], s_cnt[i]);
        }
    }
}

__global__ void finalize_kernel(const float* __restrict__ ws, float* __restrict__ out) {
    const int c = threadIdx.x;
    if (c < N_CLASSES) {
        float cnt = ws[N_CLASSES + c];
        out[c] = (cnt > 0.f) ? ws[c] / cnt : 0.0f;
    }
}

extern "C" void kernel_launch(void* const* d_in, const int* in_sizes, int n_in,
                              void* d_out, int out_size, void* d_ws, size_t ws_size,
                              hipStream_t stream) {
    const float* y_hat = (const float*)d_in[0];
    const float* y     = (const float*)d_in[1];
    float* ws  = (float*)d_ws;
    float* out = (float*)d_out;
    const int B = in_sizes[0] / N_CLASSES;

    (void)hipMemsetAsync(d_ws, 0, 2 * N_CLASSES * sizeof(float), stream);

    const int blocks = 4096;  // 2x residency -> scheduler rebalances the 3-vs-4-iter tail
    class_loss_kernel<<<blocks, 256, 0, stream>>>(y_hat, y, ws, B);
    finalize_kernel<<<1, N_CLASSES, 0, stream>>>(ws, out);
}